// Round 7
// baseline (162.419 us; speedup 1.0000x reference)
//
#include <hip/hip_runtime.h>

#define BB 4096
#define TT 10
#define SS 301
#define HH 5
#define OO 3

// Raw v_rcp_f32 (~1 ulp) instead of IEEE div sequence.
__device__ __forceinline__ float fast_rcp(float x) {
    return __builtin_amdgcn_rcpf(x);
}
__device__ __forceinline__ float sigmoidf_fast(float x) {
    // 1/(1+e^-x); rcp(inf)=0 handles the saturated tail.
    return fast_rcp(1.0f + __expf(-x));
}
// overflow-safe tanh: 1 - 2/(e^{2x}+1); e->inf gives 1, e->0 gives -1
__device__ __forceinline__ float tanhf_fast(float x) {
    return __fmaf_rn(-2.0f, fast_rcp(__expf(2.0f * x) + 1.0f), 1.0f);
}

// Pin 5 floats into explicit PHYSICAL VGPRs. Unlike generic "+v" (which only
// forces transient materialization -- R6's failure: VGPR_Count=68 < 110),
// a physical-register constraint at two program points brackets the live
// range in that exact register: the allocator cannot spill, remat, or fold
// the value back to SGPR between the pins.
#define PIN5(a,b,c,d,e,r0,r1,r2,r3,r4) \
    asm volatile("" : "+{v" #r0 "}"(a), "+{v" #r1 "}"(b), "+{v" #r2 "}"(c), \
                      "+{v" #r3 "}"(d), "+{v" #r4 "}"(e))

__global__ __launch_bounds__(256, 2) void gru_kernel(
    const float* __restrict__ x,
    const float* __restrict__ w_ih,
    const float* __restrict__ w_hh,
    const float* __restrict__ b_ih,
    const float* __restrict__ b_hh,
    const float* __restrict__ fc_w,
    const float* __restrict__ fc_b,
    float* __restrict__ out)
{
    const int n = blockIdx.x * blockDim.x + threadIdx.x;
    const int b = n / SS;
    const int s = n - b * SS;
    if (b >= BB) return;

    float wih[3 * HH];
    float whh[3 * HH][HH];
    float brz[2 * HH];   // merged b_ih + b_hh for r,z gates
    float bin[HH];       // b_ih for n gate (outside r*)
    float bhn[HH];       // b_hh for n gate (inside r*)

    #pragma unroll
    for (int g = 0; g < 2 * HH; ++g) brz[g] = b_ih[g] + b_hh[g];
    #pragma unroll
    for (int j = 0; j < HH; ++j) {
        bin[j] = b_ih[2 * HH + j];
        bhn[j] = b_hh[2 * HH + j];
    }
    #pragma unroll
    for (int g = 0; g < 3 * HH; ++g) {
        wih[g] = w_ih[g];   // I == 1
        #pragma unroll
        for (int k = 0; k < HH; ++k) whh[g][k] = w_hh[g * HH + k];
    }

    // v8..v22: wih | v23..v97: whh | v98..v107: brz | v108..v112: bin
    // v113..v117: bhn  (110 values, v8..v117)
    #define PIN_ALL_WEIGHTS() do {                                             \
        PIN5(wih[0],wih[1],wih[2],wih[3],wih[4],            8,9,10,11,12);     \
        PIN5(wih[5],wih[6],wih[7],wih[8],wih[9],            13,14,15,16,17);   \
        PIN5(wih[10],wih[11],wih[12],wih[13],wih[14],       18,19,20,21,22);   \
        PIN5(whh[0][0],whh[0][1],whh[0][2],whh[0][3],whh[0][4], 23,24,25,26,27); \
        PIN5(whh[1][0],whh[1][1],whh[1][2],whh[1][3],whh[1][4], 28,29,30,31,32); \
        PIN5(whh[2][0],whh[2][1],whh[2][2],whh[2][3],whh[2][4], 33,34,35,36,37); \
        PIN5(whh[3][0],whh[3][1],whh[3][2],whh[3][3],whh[3][4], 38,39,40,41,42); \
        PIN5(whh[4][0],whh[4][1],whh[4][2],whh[4][3],whh[4][4], 43,44,45,46,47); \
        PIN5(whh[5][0],whh[5][1],whh[5][2],whh[5][3],whh[5][4], 48,49,50,51,52); \
        PIN5(whh[6][0],whh[6][1],whh[6][2],whh[6][3],whh[6][4], 53,54,55,56,57); \
        PIN5(whh[7][0],whh[7][1],whh[7][2],whh[7][3],whh[7][4], 58,59,60,61,62); \
        PIN5(whh[8][0],whh[8][1],whh[8][2],whh[8][3],whh[8][4], 63,64,65,66,67); \
        PIN5(whh[9][0],whh[9][1],whh[9][2],whh[9][3],whh[9][4], 68,69,70,71,72); \
        PIN5(whh[10][0],whh[10][1],whh[10][2],whh[10][3],whh[10][4], 73,74,75,76,77); \
        PIN5(whh[11][0],whh[11][1],whh[11][2],whh[11][3],whh[11][4], 78,79,80,81,82); \
        PIN5(whh[12][0],whh[12][1],whh[12][2],whh[12][3],whh[12][4], 83,84,85,86,87); \
        PIN5(whh[13][0],whh[13][1],whh[13][2],whh[13][3],whh[13][4], 88,89,90,91,92); \
        PIN5(whh[14][0],whh[14][1],whh[14][2],whh[14][3],whh[14][4], 93,94,95,96,97); \
        PIN5(brz[0],brz[1],brz[2],brz[3],brz[4],            98,99,100,101,102); \
        PIN5(brz[5],brz[6],brz[7],brz[8],brz[9],            103,104,105,106,107); \
        PIN5(bin[0],bin[1],bin[2],bin[3],bin[4],            108,109,110,111,112); \
        PIN5(bhn[0],bhn[1],bhn[2],bhn[3],bhn[4],            113,114,115,116,117); \
    } while (0)

    PIN_ALL_WEIGHTS();   // pin #1: weights enter v8..v117

    // Preload all 10 inputs for this sample (coalesced across the wave per t).
    float xt[TT];
    const float* xp = x + (size_t)b * (TT * SS) + s;
    #pragma unroll
    for (int t = 0; t < TT; ++t) xt[t] = xp[t * SS];

    float h[HH];
    #pragma unroll
    for (int j = 0; j < HH; ++j) h[j] = 0.0f;

    #pragma unroll
    for (int t = 0; t < TT; ++t) {
        float hn[HH];
        #pragma unroll
        for (int j = 0; j < HH; ++j) {
            float ar  = __fmaf_rn(xt[t], wih[j],          brz[j]);
            float az  = __fmaf_rn(xt[t], wih[HH + j],     brz[HH + j]);
            float ain = __fmaf_rn(xt[t], wih[2 * HH + j], bin[j]);
            float ahn = bhn[j];
            #pragma unroll
            for (int k = 0; k < HH; ++k) {
                ar  = __fmaf_rn(whh[j][k],          h[k], ar);
                az  = __fmaf_rn(whh[HH + j][k],     h[k], az);
                ahn = __fmaf_rn(whh[2 * HH + j][k], h[k], ahn);
            }
            float r  = sigmoidf_fast(ar);
            float z  = sigmoidf_fast(az);
            float nv = tanhf_fast(__fmaf_rn(r, ahn, ain));
            // (1-z)*nv + z*h = z*(h - nv) + nv
            hn[j] = __fmaf_rn(z, h[j] - nv, nv);
        }
        #pragma unroll
        for (int j = 0; j < HH; ++j) h[j] = hn[j];
    }

    PIN_ALL_WEIGHTS();   // pin #2: live range spans the whole loop in v8..v117

    // y = fc(h); out[(b*O + o)*S + s]
    float* op = out + (size_t)b * (OO * SS) + s;
    #pragma unroll
    for (int o = 0; o < OO; ++o) {
        float y = fc_b[o];
        #pragma unroll
        for (int k = 0; k < HH; ++k) y = __fmaf_rn(fc_w[o * HH + k], h[k], y);
        op[o * SS] = y;
    }
}

extern "C" void kernel_launch(void* const* d_in, const int* in_sizes, int n_in,
                              void* d_out, int out_size, void* d_ws, size_t ws_size,
                              hipStream_t stream) {
    const float* x    = (const float*)d_in[0];
    const float* w_ih = (const float*)d_in[1];
    const float* w_hh = (const float*)d_in[2];
    const float* b_ih = (const float*)d_in[3];
    const float* b_hh = (const float*)d_in[4];
    const float* fc_w = (const float*)d_in[5];
    const float* fc_b = (const float*)d_in[6];
    float* out = (float*)d_out;

    const int N = BB * SS;                 // 1,232,896
    const int block = 256;
    const int grid = (N + block - 1) / block;  // 4816 exactly
    gru_kernel<<<grid, block, 0, stream>>>(x, w_ih, w_hh, b_ih, b_hh, fc_w, fc_b, out);
}

// Round 8
// 157.803 us; speedup vs baseline: 1.0293x; 1.0293x over previous
//
#include <hip/hip_runtime.h>

#define BB 4096
#define TT 10
#define SS 301
#define HH 5
#define OO 3

// Raw v_rcp_f32 (~1 ulp) instead of IEEE div sequence.
__device__ __forceinline__ float fast_rcp(float x) {
    return __builtin_amdgcn_rcpf(x);
}
__device__ __forceinline__ float sigmoidf_fast(float x) {
    // 1/(1+e^-x); rcp(inf)=0 handles the saturated tail.
    return fast_rcp(1.0f + __expf(-x));
}
// overflow-safe tanh: 1 - 2/(e^{2x}+1); e->inf gives 1, e->0 gives -1
__device__ __forceinline__ float tanhf_fast(float x) {
    return __fmaf_rn(-2.0f, fast_rcp(__expf(2.0f * x) + 1.0f), 1.0f);
}

__global__ __launch_bounds__(256) void gru_kernel(
    const float* __restrict__ x,
    const float* __restrict__ w_ih,
    const float* __restrict__ w_hh,
    const float* __restrict__ b_ih,
    const float* __restrict__ b_hh,
    const float* __restrict__ fc_w,
    const float* __restrict__ fc_b,
    float* __restrict__ out)
{
    const int n = blockIdx.x * blockDim.x + threadIdx.x;
    const int b = n / SS;
    const int s = n - b * SS;
    if (b >= BB) return;

    // Weights stay wave-uniform in SGPRs: the k-loop FMA
    //   v_fma_f32 vAcc, sWhh, vH, vAcc
    // reads exactly one SGPR -- legal as a single instruction.
    float wih[3 * HH];
    float whh[3 * HH][HH];
    // Biases are FORCED into VGPRs (23 values, holdable -- unlike R6/R7's
    // 110). Reason: the seed FMA fma(sWih, vXt, sBias) would read TWO SGPRs,
    // which is illegal (max 1 SGPR read per vector instr); at R0's 24-VGPR
    // allocation the compiler had no room for VGPR bias copies and emitted a
    // v_mov fixup per seed (~150+ extra instrs/wave). With vBias resident,
    // each seed is one v_fma_f32 v,s,v,v.
    float brz[2 * HH];   // merged b_ih + b_hh for r,z gates
    float bin[HH];       // b_ih for n gate (outside r*)
    float bhn[HH];       // b_hh for n gate (inside r*)
    float fcb[OO];

    #pragma unroll
    for (int g = 0; g < 2 * HH; ++g) brz[g] = b_ih[g] + b_hh[g];
    #pragma unroll
    for (int j = 0; j < HH; ++j) {
        bin[j] = b_ih[2 * HH + j];
        bhn[j] = b_hh[2 * HH + j];
    }
    #pragma unroll
    for (int o = 0; o < OO; ++o) fcb[o] = fc_b[o];
    #pragma unroll
    for (int g = 0; g < 3 * HH; ++g) {
        wih[g] = w_ih[g];   // I == 1
        #pragma unroll
        for (int k = 0; k < HH; ++k) whh[g][k] = w_hh[g * HH + k];
    }

    // One-time VGPR pins for the biases only (23 values). Single pin point,
    // before the loop; values are read-only afterwards.
    #pragma unroll
    for (int g = 0; g < 2 * HH; ++g) asm volatile("" : "+v"(brz[g]));
    #pragma unroll
    for (int j = 0; j < HH; ++j) {
        asm volatile("" : "+v"(bin[j]));
        asm volatile("" : "+v"(bhn[j]));
    }
    #pragma unroll
    for (int o = 0; o < OO; ++o) asm volatile("" : "+v"(fcb[o]));

    // Preload all 10 inputs for this sample (coalesced across the wave per t).
    float xt[TT];
    const float* xp = x + (size_t)b * (TT * SS) + s;
    #pragma unroll
    for (int t = 0; t < TT; ++t) xt[t] = xp[t * SS];

    float h[HH];
    #pragma unroll
    for (int j = 0; j < HH; ++j) h[j] = 0.0f;

    #pragma unroll
    for (int t = 0; t < TT; ++t) {
        float hn[HH];
        #pragma unroll
        for (int j = 0; j < HH; ++j) {
            float ar  = __fmaf_rn(xt[t], wih[j],          brz[j]);
            float az  = __fmaf_rn(xt[t], wih[HH + j],     brz[HH + j]);
            float ain = __fmaf_rn(xt[t], wih[2 * HH + j], bin[j]);
            float ahn = bhn[j];
            #pragma unroll
            for (int k = 0; k < HH; ++k) {
                ar  = __fmaf_rn(whh[j][k],          h[k], ar);
                az  = __fmaf_rn(whh[HH + j][k],     h[k], az);
                ahn = __fmaf_rn(whh[2 * HH + j][k], h[k], ahn);
            }
            float r  = sigmoidf_fast(ar);
            float z  = sigmoidf_fast(az);
            float nv = tanhf_fast(__fmaf_rn(r, ahn, ain));
            // (1-z)*nv + z*h = z*(h - nv) + nv
            hn[j] = __fmaf_rn(z, h[j] - nv, nv);
        }
        #pragma unroll
        for (int j = 0; j < HH; ++j) h[j] = hn[j];
    }

    // y = fc(h); out[(b*O + o)*S + s]
    float* op = out + (size_t)b * (OO * SS) + s;
    #pragma unroll
    for (int o = 0; o < OO; ++o) {
        float y = fcb[o];
        #pragma unroll
        for (int k = 0; k < HH; ++k) y = __fmaf_rn(fc_w[o * HH + k], h[k], y);
        op[o * SS] = y;
    }
}

extern "C" void kernel_launch(void* const* d_in, const int* in_sizes, int n_in,
                              void* d_out, int out_size, void* d_ws, size_t ws_size,
                              hipStream_t stream) {
    const float* x    = (const float*)d_in[0];
    const float* w_ih = (const float*)d_in[1];
    const float* w_hh = (const float*)d_in[2];
    const float* b_ih = (const float*)d_in[3];
    const float* b_hh = (const float*)d_in[4];
    const float* fc_w = (const float*)d_in[5];
    const float* fc_b = (const float*)d_in[6];
    float* out = (float*)d_out;

    const int N = BB * SS;                 // 1,232,896
    const int block = 256;
    const int grid = (N + block - 1) / block;  // 4816 exactly
    gru_kernel<<<grid, block, 0, stream>>>(x, w_ih, w_hh, b_ih, b_hh, fc_w, fc_b, out);
}